// Round 5
// baseline (860.732 us; speedup 1.0000x reference)
//
#include <hip/hip_runtime.h>

#define NEG_SLOPE 0.2f
#define CPAD 16   // one counter per 64B line to kill same-line atomic queueing

// ===========================================================================
// CSR build over a combined destination space:
// rows [0,n0)=S0a(x0), [n0,2n0)=S0b(x1), [2n0,2n0+n3)=S3a(x3), [2n0+n3,NT)=S3b(x2)
// counts_p is stride-16 padded; after chunk_scan it becomes the cursor array.
// ===========================================================================

__global__ __launch_bounds__(256) void hist_all(const int* __restrict__ ad0,
                                                const int* __restrict__ d1,
                                                const int* __restrict__ ad3,
                                                const int* __restrict__ d2,
                                                int E0, int E01, int E3, int E23,
                                                int n0, int n3,
                                                int* __restrict__ counts_p) {
    int T = E0 + E01 + E3 + E23;
    int stride = gridDim.x * 256;
    for (int i = blockIdx.x * 256 + threadIdx.x; i < T; i += 4 * stride) {
#pragma unroll
        for (int u = 0; u < 4; ++u) {
            int idx = i + u * stride;
            if (idx < T) {
                int j = idx, d, base;
                if (j < E0) { d = ad0[j]; base = 0; }
                else if ((j -= E0) < E01) { d = d1[j]; base = n0; }
                else if ((j -= E01) < E3) { d = ad3[j]; base = 2 * n0; }
                else { j -= E3; d = d2[j]; base = 2 * n0 + n3; }
                atomicAdd(&counts_p[(base + d) * CPAD], 1);
            }
        }
    }
}

// per-2048-row chunk sums (reads padded counts)
__global__ __launch_bounds__(256) void chunk_sum(const int* __restrict__ counts_p,
                                                 int* __restrict__ bsum, int NT) {
    __shared__ int red[256];
    int base = blockIdx.x * 2048;
    int t = threadIdx.x;
    int s = 0;
#pragma unroll
    for (int j = 0; j < 8; ++j) {
        int idx = base + j * 256 + t;
        if (idx < NT) s += counts_p[idx * CPAD];
    }
    red[t] = s;
    __syncthreads();
    for (int off = 128; off > 0; off >>= 1) {
        if (t < off) red[t] += red[t + off];
        __syncthreads();
    }
    if (t == 0) bsum[blockIdx.x] = red[0];
}

// exclusive scan of chunk sums (nb <= 256)
__global__ __launch_bounds__(256) void scan_bsum(const int* __restrict__ bsum,
                                                 int* __restrict__ bbase, int nb) {
    __shared__ int sh[256];
    int t = threadIdx.x;
    int v = (t < nb) ? bsum[t] : 0;
    sh[t] = v;
    __syncthreads();
    for (int off = 1; off < 256; off <<= 1) {
        int add = (t >= off) ? sh[t - off] : 0;
        __syncthreads();
        sh[t] += add;
        __syncthreads();
    }
    if (t < nb) bbase[t] = sh[t] - v;  // exclusive
}

// per-chunk exclusive scan; writes dense offsets and turns counts_p into cursors
__global__ __launch_bounds__(256) void chunk_scan(int* __restrict__ counts_p,
                                                  const int* __restrict__ bbase,
                                                  int* __restrict__ offsets,
                                                  int NT, int E_total) {
    __shared__ int tsum[256];
    int t = threadIdx.x;
    int base = blockIdx.x * 2048 + t * 8;
    int v[8];
    int s = 0;
#pragma unroll
    for (int j = 0; j < 8; ++j) {
        int idx = base + j;
        v[j] = (idx < NT) ? counts_p[idx * CPAD] : 0;
        s += v[j];
    }
    tsum[t] = s;
    __syncthreads();
    for (int off = 1; off < 256; off <<= 1) {
        int add = (t >= off) ? tsum[t - off] : 0;
        __syncthreads();
        tsum[t] += add;
        __syncthreads();
    }
    int run = bbase[blockIdx.x] + tsum[t] - s;
#pragma unroll
    for (int j = 0; j < 8; ++j) {
        int idx = base + j;
        if (idx < NT) { offsets[idx] = run; counts_p[idx * CPAD] = run; }
        run += v[j];
    }
    if (blockIdx.x == 0 && t == 0) offsets[NT] = E_total;
}

__global__ __launch_bounds__(256) void fill_all(const int* __restrict__ ad0,
                                                const int* __restrict__ as0,
                                                const int* __restrict__ d1,
                                                const int* __restrict__ s1,
                                                const int* __restrict__ ad3,
                                                const int* __restrict__ as3,
                                                const int* __restrict__ d2,
                                                const int* __restrict__ s2,
                                                int E0, int E01, int E3, int E23,
                                                int n0, int n3,
                                                int* __restrict__ cursors_p,
                                                int* __restrict__ edge_src) {
    int T = E0 + E01 + E3 + E23;
    int stride = gridDim.x * 256;
    for (int i = blockIdx.x * 256 + threadIdx.x; i < T; i += 4 * stride) {
        int dv[4], sv[4];
        bool ok[4];
#pragma unroll
        for (int u = 0; u < 4; ++u) {
            int idx = i + u * stride;
            ok[u] = idx < T;
            if (ok[u]) {
                int j = idx, d, s, base;
                if (j < E0) { d = ad0[j]; s = as0[j]; base = 0; }
                else if ((j -= E0) < E01) { d = d1[j]; s = s1[j]; base = n0; }
                else if ((j -= E01) < E3) { d = ad3[j]; s = as3[j]; base = 2 * n0; }
                else { j -= E3; d = d2[j]; s = s2[j]; base = 2 * n0 + n3; }
                dv[u] = base + d;
                sv[u] = s;
            }
        }
        int pos[4];
#pragma unroll
        for (int u = 0; u < 4; ++u)
            if (ok[u]) pos[u] = atomicAdd(&cursors_p[dv[u] * CPAD], 1);
#pragma unroll
        for (int u = 0; u < 4; ++u)
            if (ok[u]) __builtin_nontemporal_store(sv[u], &edge_src[pos[u]]);
    }
}

// ===========================================================================
// gather-reduce, wide: one 64-lane wave per dest row; 16 lanes x float4 per
// edge -> 4 edges per VMEM instruction, 8 edges in flight per iteration.
// ===========================================================================
__global__ __launch_bounds__(256) void gather_kernel(const int* __restrict__ offsets,
                                                     const int* __restrict__ edge_src,
                                                     const float* __restrict__ x0,
                                                     const float* __restrict__ x1,
                                                     const float* __restrict__ x2,
                                                     const float* __restrict__ x3,
                                                     float* __restrict__ agg0,
                                                     float* __restrict__ agg3,
                                                     int n0, int n3) {
    const int NT = 2 * n0 + 2 * n3;
    int row = blockIdx.x * 4 + (threadIdx.x >> 6);
    if (row >= NT) return;
    int lane = threadIdx.x & 63;
    int g = lane >> 4;          // edge group 0..3
    int c4 = (lane & 15) * 4;   // column within the 64-wide source row
    const float* xs;
    float* outp;
    if (row < n0)               { xs = x0; outp = &agg0[(size_t)row * 128]; }
    else if (row < 2 * n0)      { xs = x1; outp = &agg0[(size_t)(row - n0) * 128 + 64]; }
    else if (row < 2 * n0 + n3) { xs = x3; outp = &agg3[(size_t)(row - 2 * n0) * 128]; }
    else                        { xs = x2; outp = &agg3[(size_t)(row - 2 * n0 - n3) * 128 + 64]; }

    int beg = offsets[row], end = offsets[row + 1];
    float4 acc = make_float4(0.f, 0.f, 0.f, 0.f);
    int k = beg;
    for (; k + 8 <= end; k += 8) {
        int i0 = edge_src[k + g];
        int i1 = edge_src[k + 4 + g];
        float4 a = *(const float4*)&xs[(size_t)i0 * 64 + c4];
        float4 b = *(const float4*)&xs[(size_t)i1 * 64 + c4];
        acc.x += a.x; acc.y += a.y; acc.z += a.z; acc.w += a.w;
        acc.x += b.x; acc.y += b.y; acc.z += b.z; acc.w += b.w;
    }
    int rem = end - k;          // 0..7
    if (g < rem) {
        int i0 = edge_src[k + g];
        float4 a = *(const float4*)&xs[(size_t)i0 * 64 + c4];
        acc.x += a.x; acc.y += a.y; acc.z += a.z; acc.w += a.w;
    }
    if (rem > 4 && g < rem - 4) {
        int i1 = edge_src[k + 4 + g];
        float4 b = *(const float4*)&xs[(size_t)i1 * 64 + c4];
        acc.x += b.x; acc.y += b.y; acc.z += b.z; acc.w += b.w;
    }
#pragma unroll
    for (int d = 16; d < 64; d <<= 1) {
        acc.x += __shfl_xor(acc.x, d, 64);
        acc.y += __shfl_xor(acc.y, d, 64);
        acc.z += __shfl_xor(acc.z, d, 64);
        acc.w += __shfl_xor(acc.w, d, 64);
    }
    if (g == 0) *(float4*)&outp[c4] = acc;
}

// ===========================================================================
// combine_w2: WC0 = [W_hbs0 @ F0^T ; W_s01 @ F0^T], WC3 likewise; one launch.
// ===========================================================================
__global__ __launch_bounds__(256) void combine_w2(const float* __restrict__ Wtop0,
                                                  const float* __restrict__ Wbot0,
                                                  const float* __restrict__ F0,
                                                  float* __restrict__ WC0,
                                                  const float* __restrict__ Wtop3,
                                                  const float* __restrict__ Wbot3,
                                                  const float* __restrict__ F3,
                                                  float* __restrict__ WC3) {
    int gi = blockIdx.x * 256 + threadIdx.x;   // 0..32767
    int which = gi >> 14;
    int i = gi & 16383;
    const float* Wtop = which ? Wtop3 : Wtop0;
    const float* Wbot = which ? Wbot3 : Wbot0;
    const float* F = which ? F3 : F0;
    float* WC = which ? WC3 : WC0;
    int k = i >> 7;
    int c = i & 127;
    const float* wrow = (k < 64) ? &Wtop[(size_t)k * 128] : &Wbot[(size_t)(k - 64) * 128];
    const float* frow = &F[(size_t)c * 128];
    float s = 0.f;
#pragma unroll 8
    for (int j = 0; j < 128; j += 4) {
        float4 w = *(const float4*)&wrow[j];
        float4 f = *(const float4*)&frow[j];
        s = fmaf(w.x, f.x, s);
        s = fmaf(w.y, f.y, s);
        s = fmaf(w.z, f.z, s);
        s = fmaf(w.w, f.w, s);
    }
    WC[(size_t)k * 128 + c] = s;
}

// ===========================================================================
// fc_lrelu: Y[n x 128] = lrelu(A[n x 128] @ WC + b); WC k-major.
// ===========================================================================
__global__ __launch_bounds__(256) void fc_lrelu(const float* __restrict__ A,
                                                const float* __restrict__ WC,
                                                const float* __restrict__ bias,
                                                float* __restrict__ Y, int n) {
    __shared__ float WS[64][128];
    __shared__ float XS[64][68];
    const int t = threadIdx.x;
    const int row0 = blockIdx.x * 64;
    const int c = (t & 31) * 4;
    const int rbase = (t >> 5) * 8;
    float acc[8][4];
#pragma unroll
    for (int i = 0; i < 8; ++i)
#pragma unroll
        for (int j = 0; j < 4; ++j) acc[i][j] = 0.f;

    for (int p = 0; p < 2; ++p) {
        __syncthreads();
        const float4* Wp4 = (const float4*)(WC + (size_t)p * 64 * 128);
        float4* WS4 = (float4*)&WS[0][0];
        for (int i = t; i < 2048; i += 256) WS4[i] = Wp4[i];
        for (int i = t; i < 64 * 16; i += 256) {
            int r = i >> 4, c4 = i & 15;
            float4 v = make_float4(0.f, 0.f, 0.f, 0.f);
            if (row0 + r < n)
                v = *(const float4*)&A[(size_t)(row0 + r) * 128 + p * 64 + c4 * 4];
            *(float4*)&XS[r][c4 * 4] = v;
        }
        __syncthreads();

#pragma unroll 4
        for (int k = 0; k < 64; k += 4) {
            float4 w[4];
            w[0] = *(const float4*)&WS[k + 0][c];
            w[1] = *(const float4*)&WS[k + 1][c];
            w[2] = *(const float4*)&WS[k + 2][c];
            w[3] = *(const float4*)&WS[k + 3][c];
#pragma unroll
            for (int i = 0; i < 8; ++i) {
                float4 x = *(const float4*)&XS[rbase + i][k];
                float xs[4] = {x.x, x.y, x.z, x.w};
#pragma unroll
                for (int kk = 0; kk < 4; ++kk) {
                    acc[i][0] = fmaf(xs[kk], w[kk].x, acc[i][0]);
                    acc[i][1] = fmaf(xs[kk], w[kk].y, acc[i][1]);
                    acc[i][2] = fmaf(xs[kk], w[kk].z, acc[i][2]);
                    acc[i][3] = fmaf(xs[kk], w[kk].w, acc[i][3]);
                }
            }
        }
    }

    float4 b = *(const float4*)&bias[c];
    float bs[4] = {b.x, b.y, b.z, b.w};
#pragma unroll
    for (int i = 0; i < 8; ++i) {
        int r = row0 + rbase + i;
        if (r < n) {
            float o[4];
#pragma unroll
            for (int j = 0; j < 4; ++j) {
                float v = acc[i][j] + bs[j];
                o[j] = v > 0.f ? v : NEG_SLOPE * v;
            }
            *(float4*)&Y[(size_t)r * 128 + c] = make_float4(o[0], o[1], o[2], o[3]);
        }
    }
}

// one kernel for all three passthrough copies (float4 granularity)
__global__ __launch_bounds__(256) void copy_all(const float4* __restrict__ s1, float4* __restrict__ o1, int m1,
                                                const float4* __restrict__ s2, float4* __restrict__ o2, int m2,
                                                const float4* __restrict__ s4, float4* __restrict__ o4, int m4) {
    int total = m1 + m2 + m4;
    int i = blockIdx.x * 256 + threadIdx.x;
    int stride = gridDim.x * 256;
    for (; i < total; i += stride) {
        int j = i;
        if (j < m1) { o1[j] = s1[j]; }
        else if ((j -= m1) < m2) { o2[j] = s2[j]; }
        else { j -= m2; o4[j] = s4[j]; }
    }
}

extern "C" void kernel_launch(void* const* d_in, const int* in_sizes, int n_in,
                              void* d_out, int out_size, void* d_ws, size_t ws_size,
                              hipStream_t stream) {
    const float* x0 = (const float*)d_in[0];
    const float* x1 = (const float*)d_in[1];
    const float* x2 = (const float*)d_in[2];
    const float* x3 = (const float*)d_in[3];
    const float* x4 = (const float*)d_in[4];
    const int* adj0 = (const int*)d_in[5];
    const int* adj3 = (const int*)d_in[6];
    const int* inc01_t = (const int*)d_in[7];
    const int* inc01_s = (const int*)d_in[8];
    const int* inc23_t = (const int*)d_in[9];
    const int* inc23_s = (const int*)d_in[10];
    const float* W_hbs0 = (const float*)d_in[11];
    const float* W_hbs3 = (const float*)d_in[12];
    const float* W_s01 = (const float*)d_in[13];
    const float* W_t23 = (const float*)d_in[14];
    const float* fc0_W = (const float*)d_in[15];
    const float* fc0_b = (const float*)d_in[16];
    const float* fc3_W = (const float*)d_in[17];
    const float* fc3_b = (const float*)d_in[18];

    const int n0 = in_sizes[0] / 64, n1 = in_sizes[1] / 64;
    const int n2 = in_sizes[2] / 64, n3 = in_sizes[3] / 64, n4 = in_sizes[4] / 64;
    const int E0 = in_sizes[5] / 2, E3 = in_sizes[6] / 2;
    const int E01 = in_sizes[7], E23 = in_sizes[9];
    const int NT = 2 * n0 + 2 * n3;
    const int E_total = E0 + E01 + E3 + E23;
    const int nb = (NT + 2047) / 2048;

    // workspace layout
    float* ws = (float*)d_ws;
    size_t off = 0;
    float* agg0 = ws + off; off += (size_t)n0 * 128;
    float* agg3 = ws + off; off += (size_t)n3 * 128;
    float* wc0 = ws + off;  off += 16384;
    float* wc3 = ws + off;  off += 16384;
    int* counts_p = (int*)(ws + off); off += (size_t)NT * CPAD;  // padded counts->cursors
    int* offsets = (int*)(ws + off);  off += NT + 1;
    int* bsum = (int*)(ws + off);     off += 256;
    int* bbase = (int*)(ws + off);    off += 256;
    int* edge_src = (int*)(ws + off); off += E_total;

    float* out = (float*)d_out;
    float* o_x0 = out;
    float* o_x1 = o_x0 + (size_t)n0 * 128;
    float* o_x2 = o_x1 + (size_t)n1 * 64;
    float* o_x3 = o_x2 + (size_t)n2 * 64;
    float* o_x4 = o_x3 + (size_t)n3 * 128;

    // ---- CSR build ----
    hipMemsetAsync(counts_p, 0, (size_t)NT * CPAD * sizeof(int), stream);
    hist_all<<<2048, 256, 0, stream>>>(
        adj0, inc01_t, adj3, inc23_s, E0, E01, E3, E23, n0, n3, counts_p);
    chunk_sum<<<nb, 256, 0, stream>>>(counts_p, bsum, NT);
    scan_bsum<<<1, 256, 0, stream>>>(bsum, bbase, nb);
    chunk_scan<<<nb, 256, 0, stream>>>(counts_p, bbase, offsets, NT, E_total);
    fill_all<<<2048, 256, 0, stream>>>(
        adj0, adj0 + E0, inc01_t, inc01_s, adj3, adj3 + E3, inc23_s, inc23_t,
        E0, E01, E3, E23, n0, n3, counts_p, edge_src);

    // ---- gather-reduce (writes agg0/agg3 fully) ----
    gather_kernel<<<(NT + 3) / 4, 256, 0, stream>>>(offsets, edge_src, x0, x1, x2, x3,
                                                    agg0, agg3, n0, n3);

    // ---- combined weights + fused FC ----
    combine_w2<<<128, 256, 0, stream>>>(W_hbs0, W_s01, fc0_W, wc0,
                                        W_hbs3, W_t23, fc3_W, wc3);
    fc_lrelu<<<(n0 + 63) / 64, 256, 0, stream>>>(agg0, wc0, fc0_b, o_x0, n0);
    fc_lrelu<<<(n3 + 63) / 64, 256, 0, stream>>>(agg3, wc3, fc3_b, o_x3, n3);

    // ---- passthrough outputs (one kernel) ----
    copy_all<<<8192, 256, 0, stream>>>((const float4*)x1, (float4*)o_x1, n1 * 16,
                                       (const float4*)x2, (float4*)o_x2, n2 * 16,
                                       (const float4*)x4, (float4*)o_x4, n4 * 16);
}

// Round 7
// 726.319 us; speedup vs baseline: 1.1851x; 1.1851x over previous
//
#include <hip/hip_runtime.h>

#define NEG_SLOPE 0.2f
#define NPART 16   // dest partitions for fill; %16 keeps each partition on one XCD

// ===========================================================================
// CSR build over a combined destination space:
// rows [0,n0)=S0a(x0), [n0,2n0)=S0b(x1), [2n0,2n0+n3)=S3a(x3), [2n0+n3,NT)=S3b(x2)
// ===========================================================================

__global__ __launch_bounds__(256) void hist_all(const int* __restrict__ ad0,
                                                const int* __restrict__ d1,
                                                const int* __restrict__ ad3,
                                                const int* __restrict__ d2,
                                                int E0, int E01, int E3, int E23,
                                                int n0, int n3,
                                                int* __restrict__ counts) {
    int T = E0 + E01 + E3 + E23;
    int i = blockIdx.x * 256 + threadIdx.x;
    int stride = gridDim.x * 256;
    for (; i < T; i += stride) {
        int j = i, d, base;
        if (j < E0) { d = ad0[j]; base = 0; }
        else if ((j -= E0) < E01) { d = d1[j]; base = n0; }
        else if ((j -= E01) < E3) { d = ad3[j]; base = 2 * n0; }
        else { j -= E3; d = d2[j]; base = 2 * n0 + n3; }
        atomicAdd(&counts[base + d], 1);
    }
}

// per-2048-row chunk sums
__global__ __launch_bounds__(256) void chunk_sum(const int* __restrict__ counts,
                                                 int* __restrict__ bsum, int NT) {
    __shared__ int red[256];
    int base = blockIdx.x * 2048;
    int t = threadIdx.x;
    int s = 0;
#pragma unroll
    for (int j = 0; j < 8; ++j) {
        int idx = base + j * 256 + t;
        if (idx < NT) s += counts[idx];
    }
    red[t] = s;
    __syncthreads();
    for (int off = 128; off > 0; off >>= 1) {
        if (t < off) red[t] += red[t + off];
        __syncthreads();
    }
    if (t == 0) bsum[blockIdx.x] = red[0];
}

// exclusive scan of chunk sums (nb <= 256)
__global__ __launch_bounds__(256) void scan_bsum(const int* __restrict__ bsum,
                                                 int* __restrict__ bbase, int nb) {
    __shared__ int sh[256];
    int t = threadIdx.x;
    int v = (t < nb) ? bsum[t] : 0;
    sh[t] = v;
    __syncthreads();
    for (int off = 1; off < 256; off <<= 1) {
        int add = (t >= off) ? sh[t - off] : 0;
        __syncthreads();
        sh[t] += add;
        __syncthreads();
    }
    if (t < nb) bbase[t] = sh[t] - v;  // exclusive
}

// per-chunk exclusive scan + chunk base; writes offsets AND cursors
__global__ __launch_bounds__(256) void chunk_scan(const int* __restrict__ counts,
                                                  const int* __restrict__ bbase,
                                                  int* __restrict__ offsets,
                                                  int* __restrict__ cursors,
                                                  int NT, int E_total) {
    __shared__ int tsum[256];
    int t = threadIdx.x;
    int base = blockIdx.x * 2048 + t * 8;
    int v[8];
    int s = 0;
#pragma unroll
    for (int j = 0; j < 8; ++j) {
        int idx = base + j;
        v[j] = (idx < NT) ? counts[idx] : 0;
        s += v[j];
    }
    tsum[t] = s;
    __syncthreads();
    for (int off = 1; off < 256; off <<= 1) {
        int add = (t >= off) ? tsum[t - off] : 0;
        __syncthreads();
        tsum[t] += add;
        __syncthreads();
    }
    int run = bbase[blockIdx.x] + tsum[t] - s;
#pragma unroll
    for (int j = 0; j < 8; ++j) {
        int idx = base + j;
        if (idx < NT) { offsets[idx] = run; cursors[idx] = run; }
        run += v[j];
    }
    if (blockIdx.x == 0 && t == 0) offsets[NT] = E_total;
}

// ===========================================================================
// fill, dest-partitioned: blocks with blockIdx%16==p handle only dests in
// [p*PS,(p+1)*PS). Same-partition blocks share one XCD (p%8), so the 1.2 MB
// edge_src window stays L2-resident and slot-writes merge into full lines
// before eviction (kills the partial-line RMW traffic).
// ===========================================================================
__global__ __launch_bounds__(256) void fill_part(const int* __restrict__ ad0,
                                                 const int* __restrict__ as0,
                                                 const int* __restrict__ d1,
                                                 const int* __restrict__ s1,
                                                 const int* __restrict__ ad3,
                                                 const int* __restrict__ as3,
                                                 const int* __restrict__ d2,
                                                 const int* __restrict__ s2,
                                                 int E0, int E01, int E3, int E23,
                                                 int n0, int n3, int PS,
                                                 int* __restrict__ cursors,
                                                 int* __restrict__ edge_src) {
    int T = E0 + E01 + E3 + E23;
    int p = blockIdx.x & (NPART - 1);       // partition (fixes the XCD)
    int bp = blockIdx.x / NPART;            // rank within partition cohort
    int nbp = gridDim.x / NPART;            // blocks per cohort
    int lo = p * PS, hi = lo + PS;
    int stride = nbp * 256;
    for (int i = bp * 256 + threadIdx.x; i < T; i += stride) {
        int j = i, d, base;
        if (j < E0) { d = ad0[j]; base = 0; }
        else if ((j -= E0) < E01) { d = d1[j]; base = n0; }
        else if ((j -= E01) < E3) { d = ad3[j]; base = 2 * n0; }
        else { j -= E3; d = d2[j]; base = 2 * n0 + n3; }
        int cd = base + d;
        if (cd >= lo && cd < hi) {
            int s;
            // re-derive source only for accepted edges
            int jj = i;
            if (jj < E0) s = as0[jj];
            else if ((jj -= E0) < E01) s = s1[jj];
            else if ((jj -= E01) < E3) s = as3[jj];
            else { jj -= E3; s = s2[jj]; }
            int pos = atomicAdd(&cursors[cd], 1);
            edge_src[pos] = s;
        }
    }
}

// ===========================================================================
// gather4: 4 rows per wave (16 lanes x float4 each), 2 edges in flight per
// row -> 8 independent load chains per wave, no cross-lane reduce.
// Fully writes both halves of agg0/agg3 (empty rows -> zeros, no memset).
// ===========================================================================
__global__ __launch_bounds__(256) void gather4(const int* __restrict__ offsets,
                                               const int* __restrict__ edge_src,
                                               const float* __restrict__ x0,
                                               const float* __restrict__ x1,
                                               const float* __restrict__ x2,
                                               const float* __restrict__ x3,
                                               float* __restrict__ agg0,
                                               float* __restrict__ agg3,
                                               int n0, int n3) {
    const int NT = 2 * n0 + 2 * n3;
    int row = blockIdx.x * 16 + (threadIdx.x >> 4);   // 16 rows per block
    int c4 = (threadIdx.x & 15) * 4;                  // cols c4..c4+3
    if (row >= NT) return;
    const float* xs;
    float* outp;
    if (row < n0)               { xs = x0; outp = &agg0[(size_t)row * 128]; }
    else if (row < 2 * n0)      { xs = x1; outp = &agg0[(size_t)(row - n0) * 128 + 64]; }
    else if (row < 2 * n0 + n3) { xs = x3; outp = &agg3[(size_t)(row - 2 * n0) * 128]; }
    else                        { xs = x2; outp = &agg3[(size_t)(row - 2 * n0 - n3) * 128 + 64]; }

    int k = offsets[row], end = offsets[row + 1];
    float4 acc = make_float4(0.f, 0.f, 0.f, 0.f);
    for (; k + 2 <= end; k += 2) {
        int i0 = edge_src[k];
        int i1 = edge_src[k + 1];
        float4 a = *(const float4*)&xs[(size_t)i0 * 64 + c4];
        float4 b = *(const float4*)&xs[(size_t)i1 * 64 + c4];
        acc.x += a.x + b.x;
        acc.y += a.y + b.y;
        acc.z += a.z + b.z;
        acc.w += a.w + b.w;
    }
    if (k < end) {
        int i0 = edge_src[k];
        float4 a = *(const float4*)&xs[(size_t)i0 * 64 + c4];
        acc.x += a.x; acc.y += a.y; acc.z += a.z; acc.w += a.w;
    }
    *(float4*)&outp[c4] = acc;
}

// ===========================================================================
// combine_w2: WC0 = [W_hbs0 @ F0^T ; W_s01 @ F0^T], WC3 likewise; one launch.
// ===========================================================================
__global__ __launch_bounds__(256) void combine_w2(const float* __restrict__ Wtop0,
                                                  const float* __restrict__ Wbot0,
                                                  const float* __restrict__ F0,
                                                  float* __restrict__ WC0,
                                                  const float* __restrict__ Wtop3,
                                                  const float* __restrict__ Wbot3,
                                                  const float* __restrict__ F3,
                                                  float* __restrict__ WC3) {
    int gi = blockIdx.x * 256 + threadIdx.x;   // 0..32767
    int which = gi >> 14;
    int i = gi & 16383;
    const float* Wtop = which ? Wtop3 : Wtop0;
    const float* Wbot = which ? Wbot3 : Wbot0;
    const float* F = which ? F3 : F0;
    float* WC = which ? WC3 : WC0;
    int k = i >> 7;
    int c = i & 127;
    const float* wrow = (k < 64) ? &Wtop[(size_t)k * 128] : &Wbot[(size_t)(k - 64) * 128];
    const float* frow = &F[(size_t)c * 128];
    float s = 0.f;
#pragma unroll 8
    for (int j = 0; j < 128; j += 4) {
        float4 w = *(const float4*)&wrow[j];
        float4 f = *(const float4*)&frow[j];
        s = fmaf(w.x, f.x, s);
        s = fmaf(w.y, f.y, s);
        s = fmaf(w.z, f.z, s);
        s = fmaf(w.w, f.w, s);
    }
    WC[(size_t)k * 128 + c] = s;
}

// ===========================================================================
// fc_lrelu: Y[n x 128] = lrelu(A[n x 128] @ WC + b); WC k-major.
// ===========================================================================
__global__ __launch_bounds__(256) void fc_lrelu(const float* __restrict__ A,
                                                const float* __restrict__ WC,
                                                const float* __restrict__ bias,
                                                float* __restrict__ Y, int n) {
    __shared__ float WS[64][128];
    __shared__ float XS[64][68];
    const int t = threadIdx.x;
    const int row0 = blockIdx.x * 64;
    const int c = (t & 31) * 4;
    const int rbase = (t >> 5) * 8;
    float acc[8][4];
#pragma unroll
    for (int i = 0; i < 8; ++i)
#pragma unroll
        for (int j = 0; j < 4; ++j) acc[i][j] = 0.f;

    for (int p = 0; p < 2; ++p) {
        __syncthreads();
        const float4* Wp4 = (const float4*)(WC + (size_t)p * 64 * 128);
        float4* WS4 = (float4*)&WS[0][0];
        for (int i = t; i < 2048; i += 256) WS4[i] = Wp4[i];
        for (int i = t; i < 64 * 16; i += 256) {
            int r = i >> 4, c4 = i & 15;
            float4 v = make_float4(0.f, 0.f, 0.f, 0.f);
            if (row0 + r < n)
                v = *(const float4*)&A[(size_t)(row0 + r) * 128 + p * 64 + c4 * 4];
            *(float4*)&XS[r][c4 * 4] = v;
        }
        __syncthreads();

#pragma unroll 4
        for (int k = 0; k < 64; k += 4) {
            float4 w[4];
            w[0] = *(const float4*)&WS[k + 0][c];
            w[1] = *(const float4*)&WS[k + 1][c];
            w[2] = *(const float4*)&WS[k + 2][c];
            w[3] = *(const float4*)&WS[k + 3][c];
#pragma unroll
            for (int i = 0; i < 8; ++i) {
                float4 x = *(const float4*)&XS[rbase + i][k];
                float xs[4] = {x.x, x.y, x.z, x.w};
#pragma unroll
                for (int kk = 0; kk < 4; ++kk) {
                    acc[i][0] = fmaf(xs[kk], w[kk].x, acc[i][0]);
                    acc[i][1] = fmaf(xs[kk], w[kk].y, acc[i][1]);
                    acc[i][2] = fmaf(xs[kk], w[kk].z, acc[i][2]);
                    acc[i][3] = fmaf(xs[kk], w[kk].w, acc[i][3]);
                }
            }
        }
    }

    float4 b = *(const float4*)&bias[c];
    float bs[4] = {b.x, b.y, b.z, b.w};
#pragma unroll
    for (int i = 0; i < 8; ++i) {
        int r = row0 + rbase + i;
        if (r < n) {
            float o[4];
#pragma unroll
            for (int j = 0; j < 4; ++j) {
                float v = acc[i][j] + bs[j];
                o[j] = v > 0.f ? v : NEG_SLOPE * v;
            }
            *(float4*)&Y[(size_t)r * 128 + c] = make_float4(o[0], o[1], o[2], o[3]);
        }
    }
}

// one kernel for all three passthrough copies (float4 granularity)
__global__ __launch_bounds__(256) void copy_all(const float4* __restrict__ s1, float4* __restrict__ o1, int m1,
                                                const float4* __restrict__ s2, float4* __restrict__ o2, int m2,
                                                const float4* __restrict__ s4, float4* __restrict__ o4, int m4) {
    int total = m1 + m2 + m4;
    int i = blockIdx.x * 256 + threadIdx.x;
    int stride = gridDim.x * 256;
    for (; i < total; i += stride) {
        int j = i;
        if (j < m1) { o1[j] = s1[j]; }
        else if ((j -= m1) < m2) { o2[j] = s2[j]; }
        else { j -= m2; o4[j] = s4[j]; }
    }
}

extern "C" void kernel_launch(void* const* d_in, const int* in_sizes, int n_in,
                              void* d_out, int out_size, void* d_ws, size_t ws_size,
                              hipStream_t stream) {
    const float* x0 = (const float*)d_in[0];
    const float* x1 = (const float*)d_in[1];
    const float* x2 = (const float*)d_in[2];
    const float* x3 = (const float*)d_in[3];
    const float* x4 = (const float*)d_in[4];
    const int* adj0 = (const int*)d_in[5];
    const int* adj3 = (const int*)d_in[6];
    const int* inc01_t = (const int*)d_in[7];
    const int* inc01_s = (const int*)d_in[8];
    const int* inc23_t = (const int*)d_in[9];
    const int* inc23_s = (const int*)d_in[10];
    const float* W_hbs0 = (const float*)d_in[11];
    const float* W_hbs3 = (const float*)d_in[12];
    const float* W_s01 = (const float*)d_in[13];
    const float* W_t23 = (const float*)d_in[14];
    const float* fc0_W = (const float*)d_in[15];
    const float* fc0_b = (const float*)d_in[16];
    const float* fc3_W = (const float*)d_in[17];
    const float* fc3_b = (const float*)d_in[18];

    const int n0 = in_sizes[0] / 64, n1 = in_sizes[1] / 64;
    const int n2 = in_sizes[2] / 64, n3 = in_sizes[3] / 64, n4 = in_sizes[4] / 64;
    const int E0 = in_sizes[5] / 2, E3 = in_sizes[6] / 2;
    const int E01 = in_sizes[7], E23 = in_sizes[9];
    const int NT = 2 * n0 + 2 * n3;
    const int E_total = E0 + E01 + E3 + E23;
    const int nb = (NT + 2047) / 2048;
    const int PS = (NT + NPART - 1) / NPART;

    // workspace layout
    float* ws = (float*)d_ws;
    size_t off = 0;
    float* agg0 = ws + off; off += (size_t)n0 * 128;
    float* agg3 = ws + off; off += (size_t)n3 * 128;
    float* wc0 = ws + off;  off += 16384;
    float* wc3 = ws + off;  off += 16384;
    int* counts = (int*)(ws + off);   off += NT;
    int* offsets = (int*)(ws + off);  off += NT + 1;
    int* cursors = (int*)(ws + off);  off += NT;
    int* bsum = (int*)(ws + off);     off += 256;
    int* bbase = (int*)(ws + off);    off += 256;
    int* edge_src = (int*)(ws + off); off += E_total;

    float* out = (float*)d_out;
    float* o_x0 = out;
    float* o_x1 = o_x0 + (size_t)n0 * 128;
    float* o_x2 = o_x1 + (size_t)n1 * 64;
    float* o_x3 = o_x2 + (size_t)n2 * 64;
    float* o_x4 = o_x3 + (size_t)n3 * 128;

    // ---- CSR build ----
    hipMemsetAsync(counts, 0, (size_t)NT * sizeof(int), stream);
    hist_all<<<(E_total + 255) / 256, 256, 0, stream>>>(
        adj0, inc01_t, adj3, inc23_s, E0, E01, E3, E23, n0, n3, counts);
    chunk_sum<<<nb, 256, 0, stream>>>(counts, bsum, NT);
    scan_bsum<<<1, 256, 0, stream>>>(bsum, bbase, nb);
    chunk_scan<<<nb, 256, 0, stream>>>(counts, bbase, offsets, cursors, NT, E_total);
    fill_part<<<NPART * 256, 256, 0, stream>>>(
        adj0, adj0 + E0, inc01_t, inc01_s, adj3, adj3 + E3, inc23_s, inc23_t,
        E0, E01, E3, E23, n0, n3, PS, cursors, edge_src);

    // ---- gather-reduce (writes agg0/agg3 fully) ----
    gather4<<<(NT + 15) / 16, 256, 0, stream>>>(offsets, edge_src, x0, x1, x2, x3,
                                                agg0, agg3, n0, n3);

    // ---- combined weights + fused FC ----
    combine_w2<<<128, 256, 0, stream>>>(W_hbs0, W_s01, fc0_W, wc0,
                                        W_hbs3, W_t23, fc3_W, wc3);
    fc_lrelu<<<(n0 + 63) / 64, 256, 0, stream>>>(agg0, wc0, fc0_b, o_x0, n0);
    fc_lrelu<<<(n3 + 63) / 64, 256, 0, stream>>>(agg3, wc3, fc3_b, o_x3, n3);

    // ---- passthrough outputs (one kernel) ----
    copy_all<<<8192, 256, 0, stream>>>((const float4*)x1, (float4*)o_x1, n1 * 16,
                                       (const float4*)x2, (float4*)o_x2, n2 * 16,
                                       (const float4*)x4, (float4*)o_x4, n4 * 16);
}